// Round 3
// baseline (1099.258 us; speedup 1.0000x reference)
//
#include <hip/hip_runtime.h>
#include <hip/hip_bf16.h>
#include <cstdint>

#define B_SZ 1000
#define D_SZ 512
#define N_SZ 100000
#define F_SZ 50
#define NEGV -1000000.0f

#define BN 128
#define NT_N 782   // ceil(100000/128)
#define NT_B 8
#define CAP 64

#define T_OFF 0
#define CNT_OFF 4096
#define ENT_OFF 32768
#define QB_OFF (1 << 21)   // 2 MB; qb = 1024*512*2 = 1 MB -> total ws use 3 MB

typedef __bf16 bf16x8 __attribute__((ext_vector_type(8)));
typedef __bf16 bf16x2 __attribute__((ext_vector_type(2)));
typedef float f32x4 __attribute__((ext_vector_type(4)));

// ---------------- zero t/cnt regions (ws poisoned 0xAA each call) ----------
__global__ void zero_ws(int* p){ p[blockIdx.x * 256 + threadIdx.x] = 0; }

// ---------------- q f32 [1000][512] -> qb bf16 [1024][512], pad rows = 0 ---
__global__ void cvtq_kernel(const float* __restrict__ q, __bf16* __restrict__ qb){
  int g = blockIdx.x * 256 + threadIdx.x;    // 65536 threads, 8 elems each
  int row = g >> 6;
  int k0 = (g & 63) * 8;
  float4 v0 = make_float4(0.f,0.f,0.f,0.f), v1 = v0;
  if(row < B_SZ){
    v0 = *(const float4*)(q + (size_t)row * D_SZ + k0);
    v1 = *(const float4*)(q + (size_t)row * D_SZ + k0 + 4);
  }
  bf16x8 w = { (__bf16)v0.x,(__bf16)v0.y,(__bf16)v0.z,(__bf16)v0.w,
               (__bf16)v1.x,(__bf16)v1.y,(__bf16)v1.z,(__bf16)v1.w };
  *(bf16x8*)(qb + (size_t)row * D_SZ + k0) = w;
}

// ---------------- t[b] = q[b] . rhs[:, target[b]] (f32 exact) --------------
__global__ void t_kernel(const float* __restrict__ q, const float* __restrict__ rhs,
                         const int* __restrict__ target, float* __restrict__ t){
  int b = blockIdx.x;
  int tid = threadIdx.x;
  int tj = target[b];
  const float* qb = q + (size_t)b * D_SZ;
  float p = qb[tid] * rhs[(size_t)tid * N_SZ + tj]
          + qb[tid + 256] * rhs[(size_t)(tid + 256) * N_SZ + tj];
  for(int off = 32; off; off >>= 1) p += __shfl_down(p, off);
  __shared__ float red[4];
  if((tid & 63) == 0) red[tid >> 6] = p;
  __syncthreads();
  if(tid == 0) t[b] = red[0] + red[1] + red[2] + red[3];
}

// ---------------- dedupe filter∪target, bin into owning block --------------
__global__ void prep_kernel(const int* __restrict__ filt, const int* __restrict__ target,
                            const float* __restrict__ t, int* __restrict__ cnt,
                            unsigned* __restrict__ entries, float* __restrict__ out){
  int b = blockIdx.x * blockDim.x + threadIdx.x;
  if(b >= B_SZ) return;
  int idx[F_SZ + 1];
  for(int i = 0; i < F_SZ; i++) idx[i] = filt[b * F_SZ + i];
  idx[F_SZ] = target[b];
  float tb = t[b];
  int nuniq = 0;
  for(int i = 0; i <= F_SZ; i++){
    int j = idx[i];
    bool first = true;
    for(int k = 0; k < i; k++) if(idx[k] == j){ first = false; break; }
    if(!first) continue;
    nuniq++;
    int bid = (b >> 7) * NT_N + (j >> 7);
    int pos = atomicAdd(&cnt[bid], 1);
    if(pos < CAP)
      entries[(size_t)bid * CAP + pos] = (unsigned)(((b & 127) << 7) | (j & 127));
  }
  out[b] = 1.0f + ((NEGV >= tb) ? (float)nuniq : 0.0f);
}

// ---------------- B-resident fused GEMM + rank count -----------------------
// grid = 782 n-strips; each block loops over all 8 b-tiles (2 per pass, 4 passes)
__global__ __launch_bounds__(512, 4)
void main_kernel(const float* __restrict__ rhs, const __bf16* __restrict__ qb,
                 const float* __restrict__ t, const int* __restrict__ cnt,
                 const unsigned* __restrict__ entries, float* __restrict__ out){
  // B chunk [n][k]: stride 40 bf16 = 80 B = 20 dwords -> b128 frag reads 16B-aligned,
  // bank start = (20*l15 + 4*quad)%32 -> even spread, ~2-way (free, m136).
  // Staged writes bf16x2 @ bank (16g+20c+kp)%32 -> exactly 2-way (free).
  __shared__ __bf16 Bb[BN][40];
  __shared__ float tl[1024];
  __shared__ unsigned lent[8][CAP];
  __shared__ int lcnt[8];

  const int tile_n = blockIdx.x;
  const int n0 = tile_n * BN;
  const int tid = threadIdx.x;

  { int b = tid;       tl[b] = (b < B_SZ) ? t[b] : 0.f;
    b = tid + 512;     tl[b] = (b < B_SZ) ? t[b] : 0.f; }
  { int u = tid >> 6, e = tid & 63;
    lent[u][e] = entries[(size_t)(u * NT_N + tile_n) * CAP + e]; }
  if(tid < 8){ int c = cnt[tid * NT_N + tile_n]; lcnt[tid] = (c > CAP) ? CAP : c; }

  const int lane = tid & 63, quad = lane >> 4, l15 = lane & 15;
  const int wave = tid >> 6;          // 8 waves: 4 row-waves x 2 col-waves
  const int wr = (wave >> 1) * 32;    // rows [wr, wr+32)
  const int wc = (wave & 1) * 64;     // cols [wc, wc+64)

  // ---- B staging ids: g = n-quad (0..31), kp = k-pair (0..15) ----
  const int g  = tid >> 4;
  const int kp = tid & 15;
  const int nb = n0 + g * 4;
  const bool bok = nb < N_SZ;         // N%4==0: 4-col group all-in or all-out
  const float* bbase = rhs + (size_t)(2 * kp) * N_SZ + nb;
  __bf16* wp = &Bb[g * 4][kp * 2];

  const int aoff = (wr + l15) * D_SZ + quad * 8;   // per-lane A offset (elems)

  float4 v0, v1;
  const float4 fz = make_float4(0.f, 0.f, 0.f, 0.f);
  #define LOADB(KK) do { const float* p_ = bbase + (size_t)(KK) * N_SZ; \
      v0 = bok ? *(const float4*)p_ : fz; \
      v1 = bok ? *(const float4*)(p_ + N_SZ) : fz; } while(0)

  LOADB(0);
  __syncthreads();   // tl/lent visible; Bb not yet touched

  for(int grp = 0; grp < 4; grp++){
    f32x4 acc[2][2][4];
    #pragma unroll
    for(int u = 0; u < 2; u++)
      #pragma unroll
      for(int i = 0; i < 2; i++)
        #pragma unroll
        for(int j = 0; j < 4; j++)
          acc[u][i][j] = (f32x4){0.f, 0.f, 0.f, 0.f};

    for(int kt = 0; kt < 16; kt++){
      const int kk = kt * 32;
      // ---- stage prefetched regs -> LDS (cvt f32->bf16, k-pairs) ----
      {
        float a0[4] = {v0.x, v0.y, v0.z, v0.w};
        float a1[4] = {v1.x, v1.y, v1.z, v1.w};
        #pragma unroll
        for(int c = 0; c < 4; c++){
          bf16x2 w = { (__bf16)a0[c], (__bf16)a1[c] };
          *(bf16x2*)(wp + c * 40) = w;
        }
      }
      __syncthreads();
      // ---- prefetch next chunk (wraps to kk=0 for the next grp) ----
      LOADB((kk + 32) & 511);

      // ---- B frags once, reused for both b-tiles ----
      bf16x8 bf[4];
      #pragma unroll
      for(int j = 0; j < 4; j++)
        bf[j] = *(bf16x8*)&Bb[wc + j * 16 + l15][quad * 8];

      #pragma unroll
      for(int u = 0; u < 2; u++){
        const __bf16* ap = qb + (size_t)(grp * 2 + u) * 128 * D_SZ + aoff + kk;
        bf16x8 af0 = *(const bf16x8*)ap;
        #pragma unroll
        for(int j = 0; j < 4; j++)
          acc[u][0][j] = __builtin_amdgcn_mfma_f32_16x16x32_bf16(af0, bf[j], acc[u][0][j], 0, 0, 0);
        bf16x8 af1 = *(const bf16x8*)(ap + 16 * D_SZ);
        #pragma unroll
        for(int j = 0; j < 4; j++)
          acc[u][1][j] = __builtin_amdgcn_mfma_f32_16x16x32_bf16(af1, bf[j], acc[u][1][j], 0, 0, 0);
      }
      __syncthreads();   // frag reads done before next stage overwrites Bb
    }

    // ---- epilogue for b-tiles grp*2, grp*2+1 ----
    #pragma unroll
    for(int u = 0; u < 2; u++){
      const int bt = grp * 2 + u;
      int cntv[2][4];
      #pragma unroll
      for(int i = 0; i < 2; i++){
        #pragma unroll
        for(int rg = 0; rg < 4; rg++){
          int row = wr + i * 16 + quad * 4 + rg;   // 0..127 in tile
          float trow = tl[bt * 128 + row];
          int c = 0;
          #pragma unroll
          for(int j = 0; j < 4; j++){
            int ncol = n0 + wc + j * 16 + l15;
            if(ncol < N_SZ && acc[u][i][j][rg] >= trow) c++;
          }
          cntv[i][rg] = c;
        }
      }
      // subtract filtered entries owned by this block/tile
      int lc = lcnt[bt];
      for(int e = 0; e < lc; e++){
        unsigned en = lent[bt][e];
        int row128 = en >> 7;
        int col128 = en & 127;
        int rr = row128 - wr;
        int ccl = col128 - wc;
        if(rr >= 0 && rr < 32 && ccl >= 0 && ccl < 64 &&
           quad == ((rr & 15) >> 2) && l15 == (ccl & 15)){
          int ei = rr >> 4, ej = ccl >> 4, er = rr & 3;
          float trow = tl[bt * 128 + row128];
          #pragma unroll
          for(int i = 0; i < 2; i++)
            #pragma unroll
            for(int j = 0; j < 4; j++)
              #pragma unroll
              for(int rg = 0; rg < 4; rg++)
                if(i == ei && j == ej && rg == er && acc[u][i][j][rg] >= trow)
                  cntv[i][rg]--;
        }
      }
      // 16-lane column reduce, one atomic per row
      #pragma unroll
      for(int i = 0; i < 2; i++){
        #pragma unroll
        for(int rg = 0; rg < 4; rg++){
          int c = cntv[i][rg];
          c += __shfl_xor(c, 1);
          c += __shfl_xor(c, 2);
          c += __shfl_xor(c, 4);
          c += __shfl_xor(c, 8);
          if(l15 == 0){
            int bg = bt * 128 + wr + i * 16 + quad * 4 + rg;
            if(bg < B_SZ) atomicAdd(&out[bg], (float)c);
          }
        }
      }
    }
  }
  #undef LOADB
}

extern "C" void kernel_launch(void* const* d_in, const int* in_sizes, int n_in,
                              void* d_out, int out_size, void* d_ws, size_t ws_size,
                              hipStream_t stream){
  const float* q    = (const float*)d_in[0];
  const float* rhs  = (const float*)d_in[1];
  const int* filt   = (const int*)d_in[2];
  const int* target = (const int*)d_in[3];
  float* out = (float*)d_out;
  char* ws = (char*)d_ws;
  float* t          = (float*)(ws + T_OFF);
  int* cnt          = (int*)(ws + CNT_OFF);
  unsigned* entries = (unsigned*)(ws + ENT_OFF);
  __bf16* qb        = (__bf16*)(ws + QB_OFF);
  // ws usage: 2 MB + 1 MB qb = 3 MB

  zero_ws<<<32, 256, 0, stream>>>((int*)ws);
  cvtq_kernel<<<256, 256, 0, stream>>>(q, qb);
  t_kernel<<<B_SZ, 256, 0, stream>>>(q, rhs, target, t);
  prep_kernel<<<(B_SZ + 255) / 256, 256, 0, stream>>>(filt, target, t, cnt, entries, out);
  main_kernel<<<NT_N, 512, 0, stream>>>(rhs, qb, t, cnt, entries, out);
}

// Round 4
// 703.500 us; speedup vs baseline: 1.5626x; 1.5626x over previous
//
#include <hip/hip_runtime.h>
#include <hip/hip_bf16.h>
#include <cstdint>

#define B_SZ 1000
#define D_SZ 512
#define N_SZ 100000
#define F_SZ 50
#define NEGV -1000000.0f

#define BN 128
#define NT_N 782   // ceil(100000/128)
#define NT_B 8
#define CAP 64

#define T_OFF 0
#define CNT_OFF 4096
#define ENT_OFF 32768
#define QB_OFF  0x200000            // qb: 1024*512*2 = 1 MB
#define RT_OFF  0x400000            // rhsT: 100096*512*2 = 102.5 MB
#define RT_ROWS 100096              // 782*128 = 100096 (pad rows zeroed)

typedef __bf16 bf16x8 __attribute__((ext_vector_type(8)));
typedef __bf16 bf16x4 __attribute__((ext_vector_type(4)));
typedef float f32x4 __attribute__((ext_vector_type(4)));

__device__ __forceinline__ void gl_lds16(const void* g, void* l){
  __builtin_amdgcn_global_load_lds(
      (const __attribute__((address_space(1))) unsigned int*)g,
      (__attribute__((address_space(3))) unsigned int*)l, 16, 0, 0);
}
__device__ __forceinline__ float f4c(const float4& v, int c){
  switch(c){ case 0: return v.x; case 1: return v.y; case 2: return v.z; default: return v.w; }
}

// ---------------- zero t/cnt regions (ws poisoned 0xAA each call) ----------
__global__ void zero_ws(int* p){ p[blockIdx.x * 256 + threadIdx.x] = 0; }

// ---------------- q f32 [1000][512] -> qb bf16 [1024][512], pad rows 0 -----
__global__ void cvtq_kernel(const float* __restrict__ q, __bf16* __restrict__ qb){
  int g = blockIdx.x * 256 + threadIdx.x;
  int row = g >> 6;
  int k0 = (g & 63) * 8;
  float4 v0 = make_float4(0.f,0.f,0.f,0.f), v1 = v0;
  if(row < B_SZ){
    v0 = *(const float4*)(q + (size_t)row * D_SZ + k0);
    v1 = *(const float4*)(q + (size_t)row * D_SZ + k0 + 4);
  }
  bf16x8 w = { (__bf16)v0.x,(__bf16)v0.y,(__bf16)v0.z,(__bf16)v0.w,
               (__bf16)v1.x,(__bf16)v1.y,(__bf16)v1.z,(__bf16)v1.w };
  *(bf16x8*)(qb + (size_t)row * D_SZ + k0) = w;
}

// ---------------- rhs f32 [512][100000] -> rhsT bf16 [100096][512] ---------
__global__ __launch_bounds__(256)
void tconv_kernel(const float* __restrict__ rhs, __bf16* __restrict__ rhsT){
  __shared__ float tile[64][65];
  const int tn = blockIdx.x;           // 0..1563  (1564*64 = 100096)
  const int tk = blockIdx.y;           // 0..7
  const int tid = threadIdx.x;
  const int n0 = tn * 64, k0 = tk * 64;
  // read phase: coalesced along n
  {
    const int nc = (tid & 15) * 4;
    const int kr0 = tid >> 4;          // 0..15
    #pragma unroll
    for(int i = 0; i < 4; i++){
      int kr = kr0 + i * 16;
      int n = n0 + nc;
      float4 v = (n < N_SZ) ? *(const float4*)(rhs + (size_t)(k0 + kr) * N_SZ + n)
                            : make_float4(0.f,0.f,0.f,0.f);
      tile[kr][nc+0] = v.x; tile[kr][nc+1] = v.y;
      tile[kr][nc+2] = v.z; tile[kr][nc+3] = v.w;
    }
  }
  __syncthreads();
  // write phase: coalesced along k
  {
    const int nl = tid >> 2;           // 0..63
    const int kc = (tid & 3) * 16;
    float a[16];
    #pragma unroll
    for(int j = 0; j < 16; j++) a[j] = tile[kc + j][nl];
    bf16x8 w0, w1;
    #pragma unroll
    for(int j = 0; j < 8; j++){ w0[j] = (__bf16)a[j]; w1[j] = (__bf16)a[8 + j]; }
    __bf16* dst = rhsT + (size_t)(n0 + nl) * D_SZ + k0 + kc;
    *(bf16x8*)dst = w0;
    *(bf16x8*)(dst + 8) = w1;
  }
}

// ---------------- t[b] = q[b] . rhs[:, target[b]] (f32 exact) --------------
__global__ void t_kernel(const float* __restrict__ q, const float* __restrict__ rhs,
                         const int* __restrict__ target, float* __restrict__ t){
  int b = blockIdx.x;
  int tid = threadIdx.x;
  int tj = target[b];
  const float* qb = q + (size_t)b * D_SZ;
  float p = qb[tid] * rhs[(size_t)tid * N_SZ + tj]
          + qb[tid + 256] * rhs[(size_t)(tid + 256) * N_SZ + tj];
  for(int off = 32; off; off >>= 1) p += __shfl_down(p, off);
  __shared__ float red[4];
  if((tid & 63) == 0) red[tid >> 6] = p;
  __syncthreads();
  if(tid == 0) t[b] = red[0] + red[1] + red[2] + red[3];
}

// ---------------- dedupe filter∪target, bin into owning block --------------
__global__ void prep_kernel(const int* __restrict__ filt, const int* __restrict__ target,
                            const float* __restrict__ t, int* __restrict__ cnt,
                            unsigned* __restrict__ entries, float* __restrict__ out){
  int b = blockIdx.x * blockDim.x + threadIdx.x;
  if(b >= B_SZ) return;
  int idx[F_SZ + 1];
  for(int i = 0; i < F_SZ; i++) idx[i] = filt[b * F_SZ + i];
  idx[F_SZ] = target[b];
  float tb = t[b];
  int nuniq = 0;
  for(int i = 0; i <= F_SZ; i++){
    int j = idx[i];
    bool first = true;
    for(int k = 0; k < i; k++) if(idx[k] == j){ first = false; break; }
    if(!first) continue;
    nuniq++;
    int bid = (b >> 7) * NT_N + (j >> 7);
    int pos = atomicAdd(&cnt[bid], 1);
    if(pos < CAP)
      entries[(size_t)bid * CAP + pos] = (unsigned)(((b & 127) << 7) | (j & 127));
  }
  out[b] = 1.0f + ((NEGV >= tb) ? (float)nuniq : 0.0f);
}

// ---------------- fused MFMA GEMM + rank count (m97 structure) -------------
// MODE 1: B from pre-transposed bf16 rhsT via global_load_lds (needs big ws)
// MODE 0: B staged from f32 rhs with in-register cvt (fallback)
// LDS tile layout: 16B slot s = kq*128 + row  (kq = k-octet 0..3, row = m or n)
template<int MODE>
__global__ __launch_bounds__(256)
void main_kernel(const float* __restrict__ rhs, const __bf16* __restrict__ rhsT,
                 const __bf16* __restrict__ qb, const float* __restrict__ t,
                 const int* __restrict__ cnt, const unsigned* __restrict__ entries,
                 float* __restrict__ out){
  __shared__ __bf16 Ab[4096];   // 8 KB
  __shared__ __bf16 Bb[4096];   // 8 KB
  __shared__ float tl[128];
  __shared__ unsigned lent[CAP];
  __shared__ int lcnt_s;

  const int tile_b = blockIdx.x;     // fastest: 8 sharers of a B-strip co-run
  const int tile_n = blockIdx.y;
  const int bid = tile_b * NT_N + tile_n;
  const int tid = threadIdx.x;
  const int n0 = tile_n * BN;
  const int b0 = tile_b * BN;

  if(tid < 128){ int b = b0 + tid; tl[tid] = (b < B_SZ) ? t[b] : 0.f; }
  if(tid == 0){ int c = cnt[bid]; lcnt_s = (c > CAP) ? CAP : c; }
  if(tid < CAP) lent[tid] = entries[(size_t)bid * CAP + tid];

  const int lane = tid & 63, wave = tid >> 6;
  const int quad = lane >> 4, l15 = lane & 15;
  const int wr0 = (wave >> 1) * 64;
  const int wc0 = (wave & 1) * 64;

  // ---- async staging setup: wave w issues slots [2w*64,(2w+2)*64) , kq = w
  const __bf16* gA0 = qb + ((size_t)(b0 + lane) * D_SZ) + wave * 8;
  const __bf16* gA1 = gA0 + (size_t)64 * D_SZ;
  __bf16* lA0 = Ab + wave * 1024;
  __bf16* lA1 = lA0 + 512;
  const __bf16* gB0 = rhsT + ((size_t)(n0 + lane) * D_SZ) + wave * 8;
  const __bf16* gB1 = gB0 + (size_t)64 * D_SZ;
  __bf16* lB0 = Bb + wave * 1024;
  __bf16* lB1 = lB0 + 512;

  // ---- fallback B staging: thread covers k-quad kb (k=4kb..4kb+3) x 4 n ----
  const int g2 = tid & 31;           // n-quad
  const int kb = tid >> 5;           // 0..7
  const int nbc = n0 + g2 * 4;
  const bool bok = nbc < N_SZ;       // N%4==0: group all-in or all-out
  const float4 fz = make_float4(0.f, 0.f, 0.f, 0.f);
  float4 pv[4];
  if(MODE == 0){
    #pragma unroll
    for(int i = 0; i < 4; i++)
      pv[i] = bok ? *(const float4*)(rhs + (size_t)(4 * kb + i) * N_SZ + nbc) : fz;
  }

  f32x4 acc[4][4];
  #pragma unroll
  for(int i = 0; i < 4; i++)
    #pragma unroll
    for(int j = 0; j < 4; j++)
      acc[i][j] = (f32x4){0.f, 0.f, 0.f, 0.f};

  for(int kt = 0; kt < 16; kt++){
    __syncthreads();                  // prev frag reads complete
    // A: async global->LDS (bf16, zero VALU)
    gl_lds16(gA0, lA0); gl_lds16(gA1, lA1);
    gA0 += 32; gA1 += 32;
    if(MODE == 1){
      gl_lds16(gB0, lB0); gl_lds16(gB1, lB1);
      gB0 += 32; gB1 += 32;
    } else {
      // stage prefetched f32 regs -> cvt -> LDS (static indexing only)
      #pragma unroll
      for(int c = 0; c < 4; c++){
        bf16x4 w = { (__bf16)f4c(pv[0], c), (__bf16)f4c(pv[1], c),
                     (__bf16)f4c(pv[2], c), (__bf16)f4c(pv[3], c) };
        *(bf16x4*)(Bb + (kb >> 1) * 1024 + (size_t)(g2 * 4 + c) * 8 + (kb & 1) * 4) = w;
      }
    }
    __syncthreads();                  // drains vmcnt(0): tiles resident
    if(MODE == 0 && kt < 15){
      const float* p_ = rhs + (size_t)((kt + 1) * 32 + 4 * kb) * N_SZ + nbc;
      #pragma unroll
      for(int i = 0; i < 4; i++)
        pv[i] = bok ? *(const float4*)(p_ + (size_t)i * N_SZ) : fz;
    }
    // fragments: b128, slot layout -> banks spread (start = 4*(row%8))
    bf16x8 af[4], bfr[4];
    #pragma unroll
    for(int i = 0; i < 4; i++)
      af[i] = *(bf16x8*)&Ab[quad * 1024 + (size_t)(wr0 + i * 16 + l15) * 8];
    #pragma unroll
    for(int j = 0; j < 4; j++)
      bfr[j] = *(bf16x8*)&Bb[quad * 1024 + (size_t)(wc0 + j * 16 + l15) * 8];
    #pragma unroll
    for(int i = 0; i < 4; i++)
      #pragma unroll
      for(int j = 0; j < 4; j++)
        acc[i][j] = __builtin_amdgcn_mfma_f32_16x16x32_bf16(af[i], bfr[j], acc[i][j], 0, 0, 0);
  }

  // ---- epilogue: count s >= t_b (C/D layout: col=lane&15, row=quad*4+reg) --
  int cntv[4][4];
  #pragma unroll
  for(int rt = 0; rt < 4; rt++){
    #pragma unroll
    for(int r = 0; r < 4; r++){
      int row = wr0 + rt * 16 + quad * 4 + r;
      float trow = tl[row];
      int c = 0;
      #pragma unroll
      for(int ct = 0; ct < 4; ct++){
        int ncol = n0 + wc0 + ct * 16 + l15;
        if(ncol < N_SZ && acc[rt][ct][r] >= trow) c++;
      }
      cntv[rt][r] = c;
    }
  }
  int lc = lcnt_s;
  for(int e = 0; e < lc; e++){
    unsigned en = lent[e];
    int row = en >> 7;
    int col = en & 127;
    int rr = row - wr0;
    int ccl = col - wc0;
    if(rr >= 0 && rr < 64 && ccl >= 0 && ccl < 64 &&
       quad == ((rr & 15) >> 2) && l15 == (ccl & 15)){
      int rt = rr >> 4, ct = ccl >> 4, r = rr & 3;
      float trow = tl[row];
      #pragma unroll
      for(int i = 0; i < 4; i++)
        #pragma unroll
        for(int j = 0; j < 4; j++)
          #pragma unroll
          for(int k = 0; k < 4; k++)
            if(i == rt && j == ct && k == r && acc[i][j][k] >= trow)
              cntv[i][k]--;
    }
  }
  #pragma unroll
  for(int rt = 0; rt < 4; rt++){
    #pragma unroll
    for(int r = 0; r < 4; r++){
      int c = cntv[rt][r];
      c += __shfl_xor(c, 1);
      c += __shfl_xor(c, 2);
      c += __shfl_xor(c, 4);
      c += __shfl_xor(c, 8);
      if(l15 == 0){
        int bg = b0 + wr0 + rt * 16 + quad * 4 + r;
        if(bg < B_SZ) atomicAdd(&out[bg], (float)c);
      }
    }
  }
}

extern "C" void kernel_launch(void* const* d_in, const int* in_sizes, int n_in,
                              void* d_out, int out_size, void* d_ws, size_t ws_size,
                              hipStream_t stream){
  const float* q    = (const float*)d_in[0];
  const float* rhs  = (const float*)d_in[1];
  const int* filt   = (const int*)d_in[2];
  const int* target = (const int*)d_in[3];
  float* out = (float*)d_out;
  char* ws = (char*)d_ws;
  float* t          = (float*)(ws + T_OFF);
  int* cnt          = (int*)(ws + CNT_OFF);
  unsigned* entries = (unsigned*)(ws + ENT_OFF);
  __bf16* qb        = (__bf16*)(ws + QB_OFF);
  __bf16* rhsT      = (__bf16*)(ws + RT_OFF);

  const size_t need = (size_t)RT_OFF + (size_t)RT_ROWS * D_SZ * 2;   // ~106.7 MB
  const bool big = ws_size >= need;

  zero_ws<<<32, 256, 0, stream>>>((int*)ws);
  cvtq_kernel<<<256, 256, 0, stream>>>(q, qb);
  t_kernel<<<B_SZ, 256, 0, stream>>>(q, rhs, target, t);
  prep_kernel<<<(B_SZ + 255) / 256, 256, 0, stream>>>(filt, target, t, cnt, entries, out);
  dim3 grid(NT_B, NT_N);
  if(big){
    tconv_kernel<<<dim3(RT_ROWS / 64, 8), 256, 0, stream>>>(rhs, rhsT);
    main_kernel<1><<<grid, 256, 0, stream>>>(rhs, rhsT, qb, t, cnt, entries, out);
  } else {
    main_kernel<0><<<grid, 256, 0, stream>>>(rhs, rhsT, qb, t, cnt, entries, out);
  }
}